// Round 1
// 400.961 us; speedup vs baseline: 1.0776x; 1.0776x over previous
//
#include <hip/hip_runtime.h>
#include <stdint.h>

// Problem constants (reference: M,K,N = 8192,4096,4096)
#define M_DIM 8192
#define K_DIM 4096
#define N_DIM 4096

typedef __attribute__((ext_vector_type(4))) int v4i;

// ---------------------------------------------------------------------------
// Phase 1: pack int32 (harness-normalized int8 values in [-127,127]) -> int8.
// Canonical coalescing: one thread = one v4i load (16 B/lane) + one dword
// store (4 B/lane). Known-good from previous rounds — unchanged.
// ---------------------------------------------------------------------------
__device__ __forceinline__ int pack4(v4i v) {
    return (int)(((uint32_t)v.x & 0xffu)
               | (((uint32_t)v.y & 0xffu) << 8)
               | (((uint32_t)v.z & 0xffu) << 16)
               | (((uint32_t)v.w & 0xffu) << 24));
}

__global__ __launch_bounds__(256) void pack_ab(
    const int* __restrict__ srcA, const int* __restrict__ srcB,
    int* __restrict__ dstA, int* __restrict__ dstB,
    int aGroups)
{
    int g = blockIdx.x * 256 + threadIdx.x;
    const v4i* src;
    int* dst;
    if (g < aGroups) { src = (const v4i*)srcA; dst = dstA; }
    else             { src = (const v4i*)srcB; dst = dstB; g -= aGroups; }
    dst[g] = pack4(src[g]);
}

// ---------------------------------------------------------------------------
// Async global->LDS, 16B per lane. LDS dest must be wave-uniform base +
// lane*16 (m104/m108); the GLOBAL src is per-lane, so swizzled LDS layouts
// are realized by pre-swizzling the global source (m173 / rule #21).
// ---------------------------------------------------------------------------
__device__ __forceinline__ void gload16(const void* g, void* lds_p) {
    __builtin_amdgcn_global_load_lds(
        (__attribute__((address_space(1))) void*)(g),
        (__attribute__((address_space(3))) void*)(lds_p),
        16, 0, 0);
}

// ---------------------------------------------------------------------------
// Phase 2: 256x256 tile, BK=128, 8 waves (2M x 4N), 8-phase schedule with
// counted vmcnt (T3+T4), XOR bank-swizzle (T2), setprio (T5), XCD swizzle
// (T1). i8 port of the verified 256^2 8-phase bf16 template (byte-isomorphic:
// BK=128 i8 == BK=64 bf16 == 128 B/row; mfma_i32_16x16x64_i8 takes 16B/lane
// fragments just like mfma_f32_16x16x32_bf16).
//
// LDS: 2 buffers x {A,B} x {ks-half 0,1}; each half = 256 rows x 64 B = 16 KB.
//   Total 8 x 16 KB = 128 KB. Half layout: slot s (0..1023) = row*4 + sc,
//   byte = s*16. Swizzle: slot (row,sc) holds k-granule cg = sc ^ ((row>>1)&3)
//   of that row. For the fragment read (16 lanes = 16 rows at fixed cg) this
//   tiles the 32 banks exactly 2-way -> conflict-free (m136: 2-way is free).
//
// K-tiles T=0..31 (BK=128); buffer = T&1. Iteration i computes T0=2i (buf0,
// phases 1-4) and T1=2i+1 (buf1, phases 5-8); each K-tile = 4 phases:
// (ksh,qm) in {(0,0),(0,1),(1,0),(1,1)}, 16 MFMA each; B-frags read on qm==0
// phases and reused on qm==1.
//
// Stage schedule (each phase stages ONE half-tile = 2 global_load_lds,
// issued exactly one barrier-period after that region's last read):
//   p1: T1.B.ks1   p2: T1.A.ks1   p3: T2.B.ks0   p4: T2.A.ks0  + vmcnt(4)
//   p5: T2.B.ks1   p6: T2.A.ks1   p7: T3.B.ks0   p8: T3.A.ks0  + vmcnt(4)
// vmcnt(4) at p4 leaves only p3,p4's loads outstanding -> T1 fully landed
// before p5-p8 read it. vmcnt(4) at p8 leaves p7,p8's -> T2 fully landed
// before next iteration's p1-p4. Never vmcnt(0) in the main loop.
// ---------------------------------------------------------------------------
__global__ __launch_bounds__(512, 2) void int8_gemm_dequant(
    const int8_t* __restrict__ A,        // [M,K] int8 packed
    const float*  __restrict__ scale_x,  // [M]
    const int8_t* __restrict__ W,        // [N,K] int8 packed
    const float*  __restrict__ scale_w,  // [N]
    const float*  __restrict__ bias,     // [N] (harness-normalized fp16->f32)
    float*        __restrict__ out)      // [M,N] f32
{
    __shared__ __align__(16) int8_t lds[131072];   // 128 KiB

    const int t    = threadIdx.x;          // 0..511
    const int lane = t & 63;
    const int w    = t >> 6;               // wave 0..7
    const int wm   = w >> 2;               // 0..1  (M half: 128 rows)
    const int wn   = w & 3;                // 0..3  (N quarter: 64 cols)

    // T1: bijective XCD swizzle (512 % 8 == 0). Each XCD gets 64 consecutive
    // tiles = 4 rows x 16 cols -> A-panel reuse in its private L2.
    const int wg  = blockIdx.x;
    const int swz = (wg & 7) * 64 + (wg >> 3);
    const int n0  = (swz & 15) * 256;
    const int m0  = (swz >> 4) * 256;

    // Staging: thread t owns slots t and t+512 of each 16 KB half.
    // slot s -> row = s>>2, sc = s&3, global k-granule cg = sc ^ ((s>>3)&3).
    // Per wave: 16 consecutive rows x 64 contiguous bytes (granules permuted
    // among 4 lanes) -> coalescing preserved.
    const int srow = t >> 2;                        // 0..127 (2nd load: +128)
    const int scg  = (t & 3) ^ ((t >> 3) & 3);      // same for slot t+512
    const int8_t* Ap = A + (size_t)(m0 + srow) * K_DIM + scg * 16;
    const int8_t* Bp = W + (size_t)(n0 + srow) * K_DIM + scg * 16;
    int8_t* ldsb = &lds[t * 16];

    // Fragment read: lane reads row (base + (lane&15)), k-granule cg=lane>>4.
    // Swizzled slot-col = cg ^ ((row>>1)&3); base % 16 == 0 so this is the
    // per-lane constant cg ^ ((lane>>1)&3).
    const int rd = (lane & 15) * 64 + (((lane >> 4) ^ ((lane >> 1) & 3)) * 16);

    v4i acc[8][4] = {};                    // [qm*4+mt][nt]
    v4i afr[4], bfr[4];

#define HOFF(buf, mat, ksh) ((((buf) << 2) | ((mat) << 1) | (ksh)) << 14)

#define STAGE(buf, mat, ksh, OFF) do {                                        \
    const int8_t* _g = ((mat) ? Bp : Ap) + (OFF) + (ksh) * 64;                \
    int8_t* _d = ldsb + HOFF(buf, mat, ksh);                                  \
    gload16(_g, _d);                                                          \
    gload16(_g + (size_t)128 * K_DIM, _d + 8192);                             \
} while (0)

#define READ_B(buf, ksh) do {                                                 \
    const int8_t* _p = lds + HOFF(buf, 1, ksh) + wn * 4096 + rd;              \
    bfr[0] = *(const v4i*)(_p);                                               \
    bfr[1] = *(const v4i*)(_p + 1024);                                        \
    bfr[2] = *(const v4i*)(_p + 2048);                                        \
    bfr[3] = *(const v4i*)(_p + 3072);                                        \
} while (0)

#define READ_A(buf, ksh, qm) do {                                             \
    const int8_t* _p = lds + HOFF(buf, 0, ksh) + wm * 8192 + (qm) * 4096 + rd;\
    afr[0] = *(const v4i*)(_p);                                               \
    afr[1] = *(const v4i*)(_p + 1024);                                        \
    afr[2] = *(const v4i*)(_p + 2048);                                        \
    afr[3] = *(const v4i*)(_p + 3072);                                        \
} while (0)

#define MFMA_Q(qm) do {                                                       \
    _Pragma("unroll")                                                         \
    for (int mt = 0; mt < 4; ++mt) {                                          \
        _Pragma("unroll")                                                     \
        for (int nt = 0; nt < 4; ++nt) {                                      \
            acc[(qm) * 4 + mt][nt] = __builtin_amdgcn_mfma_i32_16x16x64_i8(   \
                afr[mt], bfr[nt], acc[(qm) * 4 + mt][nt], 0, 0, 0);           \
        }                                                                     \
    }                                                                         \
} while (0)

#define NOWAIT ((void)0)
#define WAIT4  asm volatile("s_waitcnt vmcnt(4)" ::: "memory")
#define WAIT0  asm volatile("s_waitcnt vmcnt(0)" ::: "memory")
#define NOSTG  ((void)0)

#define PHASE(DO_RB, buf, ksh, qm, STG, WAITV) do {                           \
    if (DO_RB) { READ_B(buf, ksh); }                                          \
    READ_A(buf, ksh, qm);                                                     \
    STG;                                                                      \
    __builtin_amdgcn_s_barrier();                                             \
    asm volatile("s_waitcnt lgkmcnt(0)" ::: "memory");                        \
    __builtin_amdgcn_s_setprio(1);                                            \
    MFMA_Q(qm);                                                               \
    __builtin_amdgcn_s_setprio(0);                                            \
    WAITV;                                                                    \
    __builtin_amdgcn_s_barrier();                                             \
} while (0)

    // Prologue: tile0 full (8 loads) + tile1 ks0 (4 loads); drain tile0,
    // leave tile1.ks0's 4 in flight (matches steady state at loop entry).
    STAGE(0, 1, 0, 0);   STAGE(0, 0, 0, 0);
    STAGE(0, 1, 1, 0);   STAGE(0, 0, 1, 0);
    STAGE(1, 1, 0, 128); STAGE(1, 0, 0, 128);
    WAIT4;
    __builtin_amdgcn_s_barrier();

    // Main loop: i = 0..14; Ap/Bp advance 256 B/iter so stage offsets are
    // immediates: T1 = +128, T2 = +256, T3 = +384 (ksh adds 64).
    for (int i = 0; i < 15; ++i) {
        PHASE(1, 0, 0, 0, STAGE(1, 1, 1, 128), NOWAIT);   // p1
        PHASE(0, 0, 0, 1, STAGE(1, 0, 1, 128), NOWAIT);   // p2
        PHASE(1, 0, 1, 0, STAGE(0, 1, 0, 256), NOWAIT);   // p3
        PHASE(0, 0, 1, 1, STAGE(0, 0, 0, 256), WAIT4);    // p4
        PHASE(1, 1, 0, 0, STAGE(0, 1, 1, 256), NOWAIT);   // p5
        PHASE(0, 1, 0, 1, STAGE(0, 0, 1, 256), NOWAIT);   // p6
        PHASE(1, 1, 1, 0, STAGE(1, 1, 0, 384), NOWAIT);   // p7
        PHASE(0, 1, 1, 1, STAGE(1, 0, 0, 384), WAIT4);    // p8
        Ap += 256; Bp += 256;
    }

    // Peeled final iteration (tiles 30,31): finish staging tile31.ks1, then
    // drain everything once (outside steady state) and compute.
    PHASE(1, 0, 0, 0, STAGE(1, 1, 1, 128), NOWAIT);
    PHASE(0, 0, 0, 1, STAGE(1, 0, 1, 128), NOWAIT);
    PHASE(1, 0, 1, 0, NOSTG, NOWAIT);
    PHASE(0, 0, 1, 1, NOSTG, WAIT0);
    PHASE(1, 1, 0, 0, NOSTG, NOWAIT);
    PHASE(0, 1, 0, 1, NOSTG, NOWAIT);
    PHASE(1, 1, 1, 0, NOSTG, NOWAIT);
    PHASE(0, 1, 1, 1, NOSTG, NOWAIT);

    // Epilogue: dequant + bias. C/D layout (16x16, dtype-independent):
    // col = lane&15, row = (lane>>4)*4 + reg.
    const int col = lane & 15;
    const int rq  = (lane >> 4) * 4;
    const float inv127sq = 1.0f / (127.0f * 127.0f);
    const int mbase = m0 + wm * 128;
    const int nbase = n0 + wn * 64;

    float sx[8][4];
#pragma unroll
    for (int ii = 0; ii < 8; ++ii) {
        const int mrow = mbase + (ii >> 2) * 64 + (ii & 3) * 16 + rq;
#pragma unroll
        for (int r = 0; r < 4; ++r) sx[ii][r] = scale_x[mrow + r];
    }

#pragma unroll
    for (int j = 0; j < 4; ++j) {
        const int n  = nbase + j * 16 + col;
        const float sw = scale_w[n] * inv127sq;
        const float bf = bias[n];
#pragma unroll
        for (int ii = 0; ii < 8; ++ii) {
            const int mrow = mbase + (ii >> 2) * 64 + (ii & 3) * 16 + rq;
#pragma unroll
            for (int r = 0; r < 4; ++r) {
                out[(size_t)(mrow + r) * N_DIM + n] =
                    (float)acc[ii][j][r] * sx[ii][r] * sw + bf;
            }
        }
    }

#undef HOFF
#undef STAGE
#undef READ_B
#undef READ_A
#undef MFMA_Q
#undef NOWAIT
#undef WAIT4
#undef WAIT0
#undef NOSTG
#undef PHASE
}

extern "C" void kernel_launch(void* const* d_in, const int* in_sizes, int n_in,
                              void* d_out, int out_size, void* d_ws, size_t ws_size,
                              hipStream_t stream) {
    // Harness normalization: integer inputs -> int32, fp16 -> f32.
    const int*   x_i32   = (const int*)  d_in[0];   // [M,K] as int32
    const float* scale_x = (const float*)d_in[1];   // [M] f32
    const int*   w_i32   = (const int*)  d_in[2];   // [N,K] as int32
    const float* scale_w = (const float*)d_in[3];   // [N] f32
    const float* bias    = (const float*)d_in[4];   // [N] f32 (from fp16)
    float* out = (float*)d_out;                     // [M,N] f32

    // Scratch layout: packed A8 then B8.
    int8_t* A8 = (int8_t*)d_ws;                          // 33,554,432 B
    int8_t* B8 = A8 + (size_t)M_DIM * K_DIM;             // 16,777,216 B

    const int a_groups = (M_DIM * K_DIM) / 4;            // 8,388,608
    const int b_groups = (N_DIM * K_DIM) / 4;            // 4,194,304
    const int total    = a_groups + b_groups;            // 12,582,912 (÷256)
    pack_ab<<<total / 256, 256, 0, stream>>>(x_i32, w_i32, (int*)A8, (int*)B8,
                                             a_groups);

    // 256x256 tiles: grid = (8192/256)*(4096/256) = 32*16 = 512 blocks.
    int8_gemm_dequant<<<512, 512, 0, stream>>>(A8, scale_x, B8, scale_w, bias, out);
}

// Round 2
// 399.013 us; speedup vs baseline: 1.0829x; 1.0049x over previous
//
#include <hip/hip_runtime.h>
#include <stdint.h>

// Problem constants (reference: M,K,N = 8192,4096,4096)
#define M_DIM 8192
#define K_DIM 4096
#define N_DIM 4096

typedef __attribute__((ext_vector_type(4))) int v4i;

// ---------------------------------------------------------------------------
// Phase 1: pack int32 (harness-normalized int8 values in [-127,127]) -> int8.
// One thread = one v4i load (16 B/lane) + one dword store. Known-good.
// ---------------------------------------------------------------------------
__device__ __forceinline__ int pack4(v4i v) {
    return (int)(((uint32_t)v.x & 0xffu)
               | (((uint32_t)v.y & 0xffu) << 8)
               | (((uint32_t)v.z & 0xffu) << 16)
               | (((uint32_t)v.w & 0xffu) << 24));
}

__global__ __launch_bounds__(256) void pack_ab(
    const int* __restrict__ srcA, const int* __restrict__ srcB,
    int* __restrict__ dstA, int* __restrict__ dstB,
    int aGroups)
{
    int g = blockIdx.x * 256 + threadIdx.x;
    const v4i* src;
    int* dst;
    if (g < aGroups) { src = (const v4i*)srcA; dst = dstA; }
    else             { src = (const v4i*)srcB; dst = dstB; g -= aGroups; }
    dst[g] = pack4(src[g]);
}

// ---------------------------------------------------------------------------
// Async global->LDS, 16B per lane. LDS dest = wave-uniform base + lane*16
// (m104/m108); swizzled layouts realized by pre-swizzling the GLOBAL source.
// ---------------------------------------------------------------------------
__device__ __forceinline__ void gload16(const void* g, void* lds_p) {
    __builtin_amdgcn_global_load_lds(
        (__attribute__((address_space(1))) void*)(g),
        (__attribute__((address_space(3))) void*)(lds_p),
        16, 0, 0);
}

// ---------------------------------------------------------------------------
// Phase 2: 256x256 tile, BK=128, 8 waves (2M x 4N), 8-phase schedule,
// counted vmcnt, XOR bank-swizzle (0 conflicts measured), setprio, XCD
// swizzle. ROUND 2 CHANGE: SINGLE barrier per phase (was 2).
//
// Why the trailing barrier is removable FOR THIS SCHEDULE (not in general):
// every STAGE(p) targets a region whose last ds_read was at phase p-2, and
// reads are issued BEFORE each phase's barrier. So between any region's
// last read (before barrier(p-2)) and its re-staging DMA (after
// barrier(p-1)) there are >= 2 barrier rendezvous even with 1 barrier/phase.
// Stage->read distances (region : last read -> staged):
//   buf1.B.ks1 : p7 -> p1   buf1.A.ks1 : p8 -> p2
//   buf0.B.ks0 : p1 -> p3   buf0.A.ks0 : p2 -> p4
//   buf0.B.ks1 : p3 -> p5   buf0.A.ks1 : p4 -> p6
//   buf1.B.ks0 : p5 -> p7   buf1.A.ks0 : p6 -> p8
// vmcnt accounting (per wave, 2 loads/STAGE): at p4 wait, outstanding =
// leftover 4 (prev p7,p8) + 8 (p1..p4) = 12 -> vmcnt(4) drains prev p7,p8
// (T1.ks0) + p1,p2 (T1.ks1): T1 fully landed before ANY wave reads it at p5
// (reads occur after barrier(p4); every wave did its own wait before that
// barrier). Same at p8 for T2. Never vmcnt(0) in the main loop.
//
// LDS: 2 buffers x {A,B} x {ks-half}; half = 256 rows x 64 B = 16 KB; total
// 128 KB. Swizzle: slot (row,sc) holds k-granule cg = sc ^ ((row>>1)&3);
// fragment reads (16 rows at fixed cg) tile 32 banks 2-way = free (m136).
// ---------------------------------------------------------------------------
__global__ __launch_bounds__(512, 2) void int8_gemm_dequant(
    const int8_t* __restrict__ A,        // [M,K] int8 packed
    const float*  __restrict__ scale_x,  // [M]
    const int8_t* __restrict__ W,        // [N,K] int8 packed
    const float*  __restrict__ scale_w,  // [N]
    const float*  __restrict__ bias,     // [N] (harness-normalized fp16->f32)
    float*        __restrict__ out)      // [M,N] f32
{
    __shared__ __align__(16) int8_t lds[131072];   // 128 KiB

    const int t    = threadIdx.x;          // 0..511
    const int lane = t & 63;
    const int w    = t >> 6;               // wave 0..7
    const int wm   = w >> 2;               // 0..1  (M half: 128 rows)
    const int wn   = w & 3;                // 0..3  (N quarter: 64 cols)

    // Bijective XCD swizzle (512 % 8 == 0): each XCD gets 4x16 tile chunk.
    const int wg  = blockIdx.x;
    const int swz = (wg & 7) * 64 + (wg >> 3);
    const int n0  = (swz & 15) * 256;
    const int m0  = (swz >> 4) * 256;

    // Staging: thread t owns slots t and t+512 of each 16 KB half.
    // slot s -> row = s>>2, sc = s&3, global k-granule cg = sc ^ ((s>>3)&3).
    const int srow = t >> 2;                        // 0..127 (2nd load: +128)
    const int scg  = (t & 3) ^ ((t >> 3) & 3);      // same for slot t+512
    const int8_t* Ap = A + (size_t)(m0 + srow) * K_DIM + scg * 16;
    const int8_t* Bp = W + (size_t)(n0 + srow) * K_DIM + scg * 16;
    int8_t* ldsb = &lds[t * 16];

    // Fragment read: lane reads row (base + (lane&15)), k-granule cg=lane>>4;
    // swizzled col = cg ^ ((lane>>1)&3) (base rows are multiples of 16).
    const int rd = (lane & 15) * 64 + (((lane >> 4) ^ ((lane >> 1) & 3)) * 16);

    v4i acc[8][4] = {};                    // [qm*4+mt][nt]
    v4i afr[4], bfr[4];

#define HOFF(buf, mat, ksh) ((((buf) << 2) | ((mat) << 1) | (ksh)) << 14)

#define STAGE(buf, mat, ksh, OFF) do {                                        \
    const int8_t* _g = ((mat) ? Bp : Ap) + (OFF) + (ksh) * 64;                \
    int8_t* _d = ldsb + HOFF(buf, mat, ksh);                                  \
    gload16(_g, _d);                                                          \
    gload16(_g + (size_t)128 * K_DIM, _d + 8192);                             \
} while (0)

#define READ_B(buf, ksh) do {                                                 \
    const int8_t* _p = lds + HOFF(buf, 1, ksh) + wn * 4096 + rd;              \
    bfr[0] = *(const v4i*)(_p);                                               \
    bfr[1] = *(const v4i*)(_p + 1024);                                        \
    bfr[2] = *(const v4i*)(_p + 2048);                                        \
    bfr[3] = *(const v4i*)(_p + 3072);                                        \
} while (0)

#define READ_A(buf, ksh, qm) do {                                             \
    const int8_t* _p = lds + HOFF(buf, 0, ksh) + wm * 8192 + (qm) * 4096 + rd;\
    afr[0] = *(const v4i*)(_p);                                               \
    afr[1] = *(const v4i*)(_p + 1024);                                        \
    afr[2] = *(const v4i*)(_p + 2048);                                        \
    afr[3] = *(const v4i*)(_p + 3072);                                        \
} while (0)

#define MFMA_Q(qm) do {                                                       \
    _Pragma("unroll")                                                         \
    for (int mt = 0; mt < 4; ++mt) {                                          \
        _Pragma("unroll")                                                     \
        for (int nt = 0; nt < 4; ++nt) {                                      \
            acc[(qm) * 4 + mt][nt] = __builtin_amdgcn_mfma_i32_16x16x64_i8(   \
                afr[mt], bfr[nt], acc[(qm) * 4 + mt][nt], 0, 0, 0);           \
        }                                                                     \
    }                                                                         \
} while (0)

#define NOWAIT ((void)0)
#define WAIT4  asm volatile("s_waitcnt vmcnt(4)" ::: "memory")
#define WAIT0  asm volatile("s_waitcnt vmcnt(0)" ::: "memory")
#define NOSTG  ((void)0)

// Single barrier per phase; counted vmcnt waits BEFORE the barrier so waves
// arrive pre-drained. reads -> stage -> [vmcnt] -> barrier -> lgkm -> MFMA.
#define PHASE(DO_RB, buf, ksh, qm, STG, WAITV) do {                           \
    if (DO_RB) { READ_B(buf, ksh); }                                          \
    READ_A(buf, ksh, qm);                                                     \
    STG;                                                                      \
    WAITV;                                                                    \
    __builtin_amdgcn_s_barrier();                                             \
    asm volatile("s_waitcnt lgkmcnt(0)" ::: "memory");                        \
    __builtin_amdgcn_s_setprio(1);                                            \
    MFMA_Q(qm);                                                               \
    __builtin_amdgcn_s_setprio(0);                                            \
} while (0)

    // Prologue: tile0 full (8 loads) + tile1 ks0 (4 loads); drain tile0,
    // leave tile1.ks0's 4 in flight (steady-state entry condition).
    STAGE(0, 1, 0, 0);   STAGE(0, 0, 0, 0);
    STAGE(0, 1, 1, 0);   STAGE(0, 0, 1, 0);
    STAGE(1, 1, 0, 128); STAGE(1, 0, 0, 128);
    WAIT4;
    __builtin_amdgcn_s_barrier();

    // Main loop: i = 0..14; Ap/Bp advance 256 B/iter so stage offsets are
    // immediates: T1 = +128, T2 = +256, T3 = +384 (ksh adds 64).
    for (int i = 0; i < 15; ++i) {
        PHASE(1, 0, 0, 0, STAGE(1, 1, 1, 128), NOWAIT);   // p1
        PHASE(0, 0, 0, 1, STAGE(1, 0, 1, 128), NOWAIT);   // p2
        PHASE(1, 0, 1, 0, STAGE(0, 1, 0, 256), NOWAIT);   // p3
        PHASE(0, 0, 1, 1, STAGE(0, 0, 0, 256), WAIT4);    // p4
        PHASE(1, 1, 0, 0, STAGE(0, 1, 1, 256), NOWAIT);   // p5
        PHASE(0, 1, 0, 1, STAGE(0, 0, 1, 256), NOWAIT);   // p6
        PHASE(1, 1, 1, 0, STAGE(1, 1, 0, 384), NOWAIT);   // p7
        PHASE(0, 1, 1, 1, STAGE(1, 0, 0, 384), WAIT4);    // p8
        Ap += 256; Bp += 256;
    }

    // Peeled final iteration (tiles 30,31): finish staging tile31.ks1, then
    // drain everything once (outside steady state) and compute.
    PHASE(1, 0, 0, 0, STAGE(1, 1, 1, 128), NOWAIT);
    PHASE(0, 0, 0, 1, STAGE(1, 0, 1, 128), NOWAIT);
    PHASE(1, 0, 1, 0, NOSTG, NOWAIT);
    PHASE(0, 0, 1, 1, NOSTG, WAIT0);
    PHASE(1, 1, 0, 0, NOSTG, NOWAIT);
    PHASE(0, 1, 0, 1, NOSTG, NOWAIT);
    PHASE(1, 1, 1, 0, NOSTG, NOWAIT);
    PHASE(0, 1, 1, 1, NOSTG, NOWAIT);

    // Epilogue: dequant + bias. C/D layout (16x16, dtype-independent):
    // col = lane&15, row = (lane>>4)*4 + reg.
    const int col = lane & 15;
    const int rq  = (lane >> 4) * 4;
    const float inv127sq = 1.0f / (127.0f * 127.0f);
    const int mbase = m0 + wm * 128;
    const int nbase = n0 + wn * 64;

    float sx[8][4];
#pragma unroll
    for (int ii = 0; ii < 8; ++ii) {
        const int mrow = mbase + (ii >> 2) * 64 + (ii & 3) * 16 + rq;
#pragma unroll
        for (int r = 0; r < 4; ++r) sx[ii][r] = scale_x[mrow + r];
    }

#pragma unroll
    for (int j = 0; j < 4; ++j) {
        const int n  = nbase + j * 16 + col;
        const float sw = scale_w[n] * inv127sq;
        const float bf = bias[n];
#pragma unroll
        for (int ii = 0; ii < 8; ++ii) {
            const int mrow = mbase + (ii >> 2) * 64 + (ii & 3) * 16 + rq;
#pragma unroll
            for (int r = 0; r < 4; ++r) {
                out[(size_t)(mrow + r) * N_DIM + n] =
                    (float)acc[ii][j][r] * sx[ii][r] * sw + bf;
            }
        }
    }

#undef HOFF
#undef STAGE
#undef READ_B
#undef READ_A
#undef MFMA_Q
#undef NOWAIT
#undef WAIT4
#undef WAIT0
#undef NOSTG
#undef PHASE
}

extern "C" void kernel_launch(void* const* d_in, const int* in_sizes, int n_in,
                              void* d_out, int out_size, void* d_ws, size_t ws_size,
                              hipStream_t stream) {
    // Harness normalization: integer inputs -> int32, fp16 -> f32.
    const int*   x_i32   = (const int*)  d_in[0];   // [M,K] as int32
    const float* scale_x = (const float*)d_in[1];   // [M] f32
    const int*   w_i32   = (const int*)  d_in[2];   // [N,K] as int32
    const float* scale_w = (const float*)d_in[3];   // [N] f32
    const float* bias    = (const float*)d_in[4];   // [N] f32 (from fp16)
    float* out = (float*)d_out;                     // [M,N] f32

    // Scratch layout: packed A8 then B8.
    int8_t* A8 = (int8_t*)d_ws;                          // 33,554,432 B
    int8_t* B8 = A8 + (size_t)M_DIM * K_DIM;             // 16,777,216 B

    const int a_groups = (M_DIM * K_DIM) / 4;            // 8,388,608
    const int b_groups = (N_DIM * K_DIM) / 4;            // 4,194,304
    const int total    = a_groups + b_groups;            // 12,582,912 (÷256)
    pack_ab<<<total / 256, 256, 0, stream>>>(x_i32, w_i32, (int*)A8, (int*)B8,
                                             a_groups);

    // 256x256 tiles: grid = (8192/256)*(4096/256) = 32*16 = 512 blocks.
    int8_gemm_dequant<<<512, 512, 0, stream>>>(A8, scale_x, B8, scale_w, bias, out);
}

// Round 3
// 395.535 us; speedup vs baseline: 1.0924x; 1.0088x over previous
//
#include <hip/hip_runtime.h>
#include <stdint.h>

// Problem constants (reference: M,K,N = 8192,4096,4096)
#define M_DIM 8192
#define K_DIM 4096
#define N_DIM 4096

typedef __attribute__((ext_vector_type(4))) int v4i;

// ---------------------------------------------------------------------------
// Phase 1: pack int32 (harness-normalized int8 values in [-127,127]) -> int8.
// One thread = one v4i load (16 B/lane) + one dword store. Known-good.
// ---------------------------------------------------------------------------
__device__ __forceinline__ int pack4(v4i v) {
    return (int)(((uint32_t)v.x & 0xffu)
               | (((uint32_t)v.y & 0xffu) << 8)
               | (((uint32_t)v.z & 0xffu) << 16)
               | (((uint32_t)v.w & 0xffu) << 24));
}

__global__ __launch_bounds__(256) void pack_ab(
    const int* __restrict__ srcA, const int* __restrict__ srcB,
    int* __restrict__ dstA, int* __restrict__ dstB,
    int aGroups)
{
    int g = blockIdx.x * 256 + threadIdx.x;
    const v4i* src;
    int* dst;
    if (g < aGroups) { src = (const v4i*)srcA; dst = dstA; }
    else             { src = (const v4i*)srcB; dst = dstB; g -= aGroups; }
    dst[g] = pack4(src[g]);
}

// ---------------------------------------------------------------------------
// Async global->LDS, 16B per lane. LDS dest = wave-uniform base + lane*16
// (m104/m108); swizzled layouts realized by pre-swizzling the GLOBAL source.
// ---------------------------------------------------------------------------
__device__ __forceinline__ void gload16(const void* g, void* lds_p) {
    __builtin_amdgcn_global_load_lds(
        (__attribute__((address_space(1))) void*)(g),
        (__attribute__((address_space(3))) void*)(lds_p),
        16, 0, 0);
}

// ---------------------------------------------------------------------------
// Phase 2: 256x256 tile, BK=128, 8 waves (2M x 4N), 8-phase schedule,
// counted vmcnt, XOR bank-swizzle (0 conflicts measured), setprio, XCD
// swizzle. ROUND 3 CHANGE: register-fragment software pipeline.
//
// R2 finding: per-phase wall ~1360 cyc = MFMA 653 + LDS-drain 576 + overhead
// -> ds_read drain and MFMA were SERIAL (each phase read its own frags, then
// lgkmcnt(0) drained while the matrix pipe idled; 1 block/CU = no cover).
// Fix: phase p issues ds_reads for phase p+1's fragments (alternate reg set)
// right after barrier(p), then MFMAs phase p's fragments (read at p-1).
// The LDS drain now hides under MFMA execution. Forced lgkmcnt(0) removed —
// compiler auto-inserts counted lgkm waits on the frag data-deps (m97 asm).
// sched_barrier(0) pins read-issue before MFMA-issue (rule #18 family).
//
// Early-read hazard audit (region : staged -> certified -> early-read):
//   buf1.B.ks1: p1 -> p4   -> read p6      buf1.A.ks1: p2 -> p4  -> read p7
//   buf0.B.ks0: p3 -> p8   -> read p8'     buf0.A.ks0: p4 -> p8  -> read p8'
//   buf0.B.ks1: p5 -> p8   -> read p2'     buf0.A.ks1: p6 -> p8  -> read p2'/p3'
//   buf1.B.ks0: p7 -> p4'  -> read p4'     buf1.A.ks0: p8 -> p4' -> read p4'/p5'
// (read-after-certification holds everywhere; the two just-in-time cases,
// buf1.ks0 at p4 and buf0.ks0 at p8, read AFTER the barrier that follows
// their certifying vmcnt(4).) Write-after-read distance >= 3 phases for all
// regions. vmcnt accounting identical to R1/R2 (verified absmax 2.4e-4).
//
// LDS: 2 buffers x {A,B} x {ks-half}; half = 256 rows x 64 B = 16 KB; total
// 128 KB. Swizzle: slot (row,sc) holds k-granule cg = sc ^ ((row>>1)&3);
// fragment reads (16 rows at fixed cg) tile 32 banks 2-way = free (m136).
// ---------------------------------------------------------------------------
__global__ __launch_bounds__(512, 2) void int8_gemm_dequant(
    const int8_t* __restrict__ A,        // [M,K] int8 packed
    const float*  __restrict__ scale_x,  // [M]
    const int8_t* __restrict__ W,        // [N,K] int8 packed
    const float*  __restrict__ scale_w,  // [N]
    const float*  __restrict__ bias,     // [N] (harness-normalized fp16->f32)
    float*        __restrict__ out)      // [M,N] f32
{
    __shared__ __align__(16) int8_t lds[131072];   // 128 KiB

    const int t    = threadIdx.x;          // 0..511
    const int lane = t & 63;
    const int w    = t >> 6;               // wave 0..7
    const int wm   = w >> 2;               // 0..1  (M half: 128 rows)
    const int wn   = w & 3;                // 0..3  (N quarter: 64 cols)

    // Bijective XCD swizzle (512 % 8 == 0): each XCD gets 4x16 tile chunk.
    const int wg  = blockIdx.x;
    const int swz = (wg & 7) * 64 + (wg >> 3);
    const int n0  = (swz & 15) * 256;
    const int m0  = (swz >> 4) * 256;

    // Staging: thread t owns slots t and t+512 of each 16 KB half.
    // slot s -> row = s>>2, sc = s&3, global k-granule cg = sc ^ ((s>>3)&3).
    const int srow = t >> 2;                        // 0..127 (2nd load: +128)
    const int scg  = (t & 3) ^ ((t >> 3) & 3);      // same for slot t+512
    const int8_t* Ap = A + (size_t)(m0 + srow) * K_DIM + scg * 16;
    const int8_t* Bp = W + (size_t)(n0 + srow) * K_DIM + scg * 16;
    int8_t* ldsb = &lds[t * 16];

    // Fragment read: lane reads row (base + (lane&15)), k-granule cg=lane>>4;
    // swizzled col = cg ^ ((lane>>1)&3) (base rows are multiples of 16).
    const int rd = (lane & 15) * 64 + (((lane >> 4) ^ ((lane >> 1) & 3)) * 16);

    v4i acc[8][4] = {};                    // [qm*4+mt][nt]
    // Double-buffered fragment sets (compile-time indexed everywhere, #20).
    v4i afr0[4], afr1[4], bfr0[4], bfr1[4];

#define HOFF(buf, mat, ksh) ((((buf) << 2) | ((mat) << 1) | (ksh)) << 14)

#define STAGE(buf, mat, ksh, OFF) do {                                        \
    const int8_t* _g = ((mat) ? Bp : Ap) + (OFF) + (ksh) * 64;                \
    int8_t* _d = ldsb + HOFF(buf, mat, ksh);                                  \
    gload16(_g, _d);                                                          \
    gload16(_g + (size_t)128 * K_DIM, _d + 8192);                             \
} while (0)

#define READ_B_TO(DST, buf, ksh) do {                                         \
    const int8_t* _p = lds + HOFF(buf, 1, ksh) + wn * 4096 + rd;              \
    DST[0] = *(const v4i*)(_p);                                               \
    DST[1] = *(const v4i*)(_p + 1024);                                        \
    DST[2] = *(const v4i*)(_p + 2048);                                        \
    DST[3] = *(const v4i*)(_p + 3072);                                        \
} while (0)

#define READ_A_TO(DST, buf, ksh, qm) do {                                     \
    const int8_t* _p = lds + HOFF(buf, 0, ksh) + wm * 8192 + (qm) * 4096 + rd;\
    DST[0] = *(const v4i*)(_p);                                               \
    DST[1] = *(const v4i*)(_p + 1024);                                        \
    DST[2] = *(const v4i*)(_p + 2048);                                        \
    DST[3] = *(const v4i*)(_p + 3072);                                        \
} while (0)

#define MFMA_Q(qm, AF, BF) do {                                               \
    _Pragma("unroll")                                                         \
    for (int mt = 0; mt < 4; ++mt) {                                          \
        _Pragma("unroll")                                                     \
        for (int nt = 0; nt < 4; ++nt) {                                      \
            acc[(qm) * 4 + mt][nt] = __builtin_amdgcn_mfma_i32_16x16x64_i8(   \
                AF[mt], BF[nt], acc[(qm) * 4 + mt][nt], 0, 0, 0);             \
        }                                                                     \
    }                                                                         \
} while (0)

#define NOWAIT ((void)0)
#define WAIT4  asm volatile("s_waitcnt vmcnt(4)" ::: "memory")
#define WAIT0  asm volatile("s_waitcnt vmcnt(0)" ::: "memory")
#define NOSTG  ((void)0)
#define NORD   ((void)0)

// Phase: stage (vmem issue) -> [counted vmcnt] -> barrier -> issue NEXT
// phase's ds_reads -> sched fence -> MFMA current frags. Current frags were
// read one phase ago, so their lgkm wait (compiler-counted) is already
// satisfied and the new reads drain UNDER the MFMA execution.
#define PH(qm, AF, BF, NEXTRD, STG, WAITV) do {                               \
    STG;                                                                      \
    WAITV;                                                                    \
    __builtin_amdgcn_s_barrier();                                             \
    NEXTRD;                                                                   \
    __builtin_amdgcn_sched_barrier(0);                                        \
    __builtin_amdgcn_s_setprio(1);                                            \
    MFMA_Q(qm, AF, BF);                                                       \
    __builtin_amdgcn_s_setprio(0);                                            \
} while (0)

    // Prologue: tile0 full (8 loads) + tile1 ks0 (4 loads); drain tile0,
    // leave tile1.ks0's 4 in flight (steady-state entry condition). Then
    // pre-read phase-1 fragments (T0 certified by the WAIT4).
    STAGE(0, 1, 0, 0);   STAGE(0, 0, 0, 0);
    STAGE(0, 1, 1, 0);   STAGE(0, 0, 1, 0);
    STAGE(1, 1, 0, 128); STAGE(1, 0, 0, 128);
    WAIT4;
    __builtin_amdgcn_s_barrier();
    READ_A_TO(afr0, 0, 0, 0);
    READ_B_TO(bfr0, 0, 0);

    // Main loop: i = 0..14; Ap/Bp advance 256 B/iter so stage offsets are
    // immediates: T1 = +128, T2 = +256, T3 = +384 (ksh adds 64).
    for (int i = 0; i < 15; ++i) {
        PH(0, afr0, bfr0, READ_A_TO(afr1, 0, 0, 1),
           STAGE(1, 1, 1, 128), NOWAIT);                               // p1
        PH(1, afr1, bfr0,
           { READ_A_TO(afr0, 0, 1, 0); READ_B_TO(bfr1, 0, 1); },
           STAGE(1, 0, 1, 128), NOWAIT);                               // p2
        PH(0, afr0, bfr1, READ_A_TO(afr1, 0, 1, 1),
           STAGE(0, 1, 0, 256), NOWAIT);                               // p3
        PH(1, afr1, bfr1,
           { READ_A_TO(afr0, 1, 0, 0); READ_B_TO(bfr0, 1, 0); },
           STAGE(0, 0, 0, 256), WAIT4);                                // p4
        PH(0, afr0, bfr0, READ_A_TO(afr1, 1, 0, 1),
           STAGE(0, 1, 1, 256), NOWAIT);                               // p5
        PH(1, afr1, bfr0,
           { READ_A_TO(afr0, 1, 1, 0); READ_B_TO(bfr1, 1, 1); },
           STAGE(0, 0, 1, 256), NOWAIT);                               // p6
        PH(0, afr0, bfr1, READ_A_TO(afr1, 1, 1, 1),
           STAGE(1, 1, 0, 384), NOWAIT);                               // p7
        PH(1, afr1, bfr1,
           { READ_A_TO(afr0, 0, 0, 0); READ_B_TO(bfr0, 0, 0); },
           STAGE(1, 0, 0, 384), WAIT4);                                // p8
        Ap += 256; Bp += 256;
    }

    // Peeled final iteration (tiles 30,31): finish staging tile31.ks1, full
    // drain once (WAIT0 certifies T31 before p4's just-in-time reads).
    PH(0, afr0, bfr0, READ_A_TO(afr1, 0, 0, 1), STAGE(1, 1, 1, 128), NOWAIT);
    PH(1, afr1, bfr0,
       { READ_A_TO(afr0, 0, 1, 0); READ_B_TO(bfr1, 0, 1); },
       STAGE(1, 0, 1, 128), NOWAIT);
    PH(0, afr0, bfr1, READ_A_TO(afr1, 0, 1, 1), NOSTG, NOWAIT);
    PH(1, afr1, bfr1,
       { READ_A_TO(afr0, 1, 0, 0); READ_B_TO(bfr0, 1, 0); },
       NOSTG, WAIT0);
    PH(0, afr0, bfr0, READ_A_TO(afr1, 1, 0, 1), NOSTG, NOWAIT);
    PH(1, afr1, bfr0,
       { READ_A_TO(afr0, 1, 1, 0); READ_B_TO(bfr1, 1, 1); },
       NOSTG, NOWAIT);
    PH(0, afr0, bfr1, READ_A_TO(afr1, 1, 1, 1), NOSTG, NOWAIT);
    PH(1, afr1, bfr1, NORD, NOSTG, NOWAIT);

    // Epilogue: dequant + bias. C/D layout (16x16, dtype-independent):
    // col = lane&15, row = (lane>>4)*4 + reg.
    const int col = lane & 15;
    const int rq  = (lane >> 4) * 4;
    const float inv127sq = 1.0f / (127.0f * 127.0f);
    const int mbase = m0 + wm * 128;
    const int nbase = n0 + wn * 64;

    float sx[8][4];
#pragma unroll
    for (int ii = 0; ii < 8; ++ii) {
        const int mrow = mbase + (ii >> 2) * 64 + (ii & 3) * 16 + rq;
#pragma unroll
        for (int r = 0; r < 4; ++r) sx[ii][r] = scale_x[mrow + r];
    }

#pragma unroll
    for (int j = 0; j < 4; ++j) {
        const int n  = nbase + j * 16 + col;
        const float sw = scale_w[n] * inv127sq;
        const float bf = bias[n];
#pragma unroll
        for (int ii = 0; ii < 8; ++ii) {
            const int mrow = mbase + (ii >> 2) * 64 + (ii & 3) * 16 + rq;
#pragma unroll
            for (int r = 0; r < 4; ++r) {
                out[(size_t)(mrow + r) * N_DIM + n] =
                    (float)acc[ii][j][r] * sx[ii][r] * sw + bf;
            }
        }
    }

#undef HOFF
#undef STAGE
#undef READ_B_TO
#undef READ_A_TO
#undef MFMA_Q
#undef NOWAIT
#undef WAIT4
#undef WAIT0
#undef NOSTG
#undef NORD
#undef PH
}

extern "C" void kernel_launch(void* const* d_in, const int* in_sizes, int n_in,
                              void* d_out, int out_size, void* d_ws, size_t ws_size,
                              hipStream_t stream) {
    // Harness normalization: integer inputs -> int32, fp16 -> f32.
    const int*   x_i32   = (const int*)  d_in[0];   // [M,K] as int32
    const float* scale_x = (const float*)d_in[1];   // [M] f32
    const int*   w_i32   = (const int*)  d_in[2];   // [N,K] as int32
    const float* scale_w = (const float*)d_in[3];   // [N] f32
    const float* bias    = (const float*)d_in[4];   // [N] f32 (from fp16)
    float* out = (float*)d_out;                     // [M,N] f32

    // Scratch layout: packed A8 then B8.
    int8_t* A8 = (int8_t*)d_ws;                          // 33,554,432 B
    int8_t* B8 = A8 + (size_t)M_DIM * K_DIM;             // 16,777,216 B

    const int a_groups = (M_DIM * K_DIM) / 4;            // 8,388,608
    const int b_groups = (N_DIM * K_DIM) / 4;            // 4,194,304
    const int total    = a_groups + b_groups;            // 12,582,912 (÷256)
    pack_ab<<<total / 256, 256, 0, stream>>>(x_i32, w_i32, (int*)A8, (int*)B8,
                                             a_groups);

    // 256x256 tiles: grid = (8192/256)*(4096/256) = 32*16 = 512 blocks.
    int8_gemm_dequant<<<512, 512, 0, stream>>>(A8, scale_x, B8, scale_w, bias, out);
}